// Round 9
// baseline (3689.957 us; speedup 1.0000x reference)
//
#include <hip/hip_runtime.h>
#include <hip/hip_bf16.h>
#include <stdint.h>

// ---------------------------------------------------------------------------
// PFGAT: [B,T,N,F]=[4,8,2048,16] transformer (causal attn over N per (b,t),
// node attn over T-slots, MLP at last slot) -> 2x GATConv -> FFN -> [B,14,N].
// fp32 I/O, fp32 compute, bf16 intermediate storage.
// R9: R8 (paired tiles + 2-row blocking) with spill fix: no min-waves
// launch bound (R8's (256,2) forced 128 VGPRs -> 2.3GB scratch traffic),
// 8-key softmax substeps to cut S-array pressure.
// ---------------------------------------------------------------------------

#define BB     4
#define TT     8
#define NN     2048
#define FIN    16
#define HID    128
#define BM     (BB*TT)            // 32 attention slices
#define PROWS  (BM*NN)            // 65536 rows
#define NHEADS 4
#define OUTCH  64
#define OUTF   14
#define NEDGE  32768
#define NEDGEB (NEDGE*BB)         // 131072
#define NNODE  (BB*NN)            // 8192
#define NETOT  (NEDGEB + NNODE)   // 139264 (edges + self loops)

#define TQ     64                 // query tile
#define TK     32                 // key tile
#define NTILE  (NN/TQ)            // 32 query tiles per slice
#define NPAIR  (NTILE/2)          // 16 pair-blocks per slice

typedef __hip_bfloat16 bf16;

__device__ __forceinline__ float b2f(bf16 v){ return __bfloat162float(v); }
__device__ __forceinline__ bf16  f2b(float f){ return __float2bfloat16(f); }
__device__ __forceinline__ float bits2f(uint32_t b){ union{uint32_t u; float f;} v; v.u=b; return v.f; }

// ---------------------------------------------------------------------------
// K1: per row: LN1 over F=16 -> k,v projections (stored bf16).
// ---------------------------------------------------------------------------
__global__ void k_kv(const float* __restrict__ x,
                     const float* __restrict__ g1, const float* __restrict__ bb1,
                     const float* __restrict__ wk, const float* __restrict__ bk,
                     const float* __restrict__ wv, const float* __restrict__ bv,
                     int in_off, bf16* __restrict__ K, bf16* __restrict__ V)
{
    const int rloc = blockIdx.x;
    const int rin  = rloc + in_off;
    const int h = threadIdx.x;       // 0..127
    __shared__ float xr[FIN], lnv[FIN];
    if (h < FIN) xr[h] = x[(size_t)rin*FIN + h];
    __syncthreads();
    float mu = 0.f;
    #pragma unroll
    for (int f = 0; f < FIN; ++f) mu += xr[f];
    mu *= (1.f/FIN);
    float var = 0.f;
    #pragma unroll
    for (int f = 0; f < FIN; ++f){ float d = xr[f]-mu; var += d*d; }
    var *= (1.f/FIN);
    const float inv = rsqrtf(var + 1e-5f);
    if (h < FIN) lnv[h] = (xr[h]-mu)*inv*g1[h] + bb1[h];
    __syncthreads();
    float ak = bk[h], av = bv[h];
    #pragma unroll
    for (int f = 0; f < FIN; ++f){
        const float l = lnv[f];
        ak += l * wk[f*HID + h];
        av += l * wv[f*HID + h];
    }
    const size_t o = (size_t)rloc*HID + h;
    K[o] = f2b(ak); V[o] = f2b(av);
}

// ---------------------------------------------------------------------------
// K2 (flash, paired + 2-row blocked, spill-free):
// block = (pair pa, slice): query tiles a=pa and b=31-pa (128 rows).
// 256 threads = qr(0..63) x cg(0..3); thread owns rows {2qr, 2qr+1} of its
// tile (qr<32 -> tile a, else tile b) and 32 channels {kk*16+cg*4+i}.
// K/V tile fp32 in LDS, interleaved-chunk reads (conflict-free, static idx);
// each read feeds both rows. Online softmax in 8-key substeps.
// Fused epilogue in two phases reusing kv as cx buffer.
// ---------------------------------------------------------------------------
__global__ __launch_bounds__(256)
void k_attn_flash(const float* __restrict__ x,
                  const bf16* __restrict__ K, const bf16* __restrict__ V,
                  const float* __restrict__ g1, const float* __restrict__ bb1,
                  const float* __restrict__ wq, const float* __restrict__ bq,
                  const float* __restrict__ skw, const float* __restrict__ skb,
                  const float* __restrict__ t_wo, const float* __restrict__ t_bo,
                  int slice_off, bf16* __restrict__ H1)
{
    const int pa    = blockIdx.x;               // 0..15
    const int q0a   = pa*TQ;
    const int q0b   = (NTILE-1-pa)*TQ;          // the big tile
    const int slice = blockIdx.y + slice_off;
    const int t  = threadIdx.x;
    const int qr = t >> 2;                      // 0..63
    const int cg = t & 3;
    const bool tileA = (qr < 32);
    const int myq0 = tileA ? q0a : q0b;
    const int tlr0 = (2*qr) & (TQ-1);           // local row in my tile (even)
    const int qi0  = myq0 + tlr0;               // global rows qi0, qi0+1

    __shared__ float xs [2*TQ][FIN];            // raw x rows (a then b)
    __shared__ float lns[2*TQ][FIN];            // LN1(x) rows
    __shared__ float kv [2*TK*HID];             // K|V tile fp32; cx in epilogue
    float4* kv4 = (float4*)kv;

    // ---- stage x rows for both tiles ----
    for (int u = t; u < TQ*FIN; u += 256){
        ((float*)xs)[u]          = x[((size_t)slice*NN + q0a)*FIN + u];
        ((float*)xs)[TQ*FIN + u] = x[((size_t)slice*NN + q0b)*FIN + u];
    }
    __syncthreads();
    // ---- LN1 per row (128 rows) ----
    if (t < 2*TQ){
        float mu = 0.f;
        #pragma unroll
        for (int f = 0; f < FIN; ++f) mu += xs[t][f];
        mu *= (1.f/FIN);
        float var = 0.f;
        #pragma unroll
        for (int f = 0; f < FIN; ++f){ float d = xs[t][f]-mu; var += d*d; }
        var *= (1.f/FIN);
        const float inv = rsqrtf(var + 1e-5f);
        #pragma unroll
        for (int f = 0; f < FIN; ++f)
            lns[t][f] = (xs[t][f]-mu)*inv*g1[f] + bb1[f];
    }
    __syncthreads();

    // ---- q for both rows (scale folded); ch = kk*16+cg*4+i ----
    float4 q0r[8], q1r[8];
    {
        const float scale = 0.08838834764831845f;   // 1/sqrt(128)
        #pragma unroll
        for (int kk = 0; kk < 8; ++kk){
            float t0[4], t1[4];
            #pragma unroll
            for (int i = 0; i < 4; ++i){
                const int ch = kk*16 + cg*4 + i;
                float a0 = bq[ch], a1 = a0;
                #pragma unroll
                for (int f = 0; f < FIN; ++f){
                    const float w = wq[f*HID + ch];
                    a0 += lns[2*qr][f]*w; a1 += lns[2*qr+1][f]*w;
                }
                t0[i] = a0*scale; t1[i] = a1*scale;
            }
            q0r[kk] = make_float4(t0[0],t0[1],t0[2],t0[3]);
            q1r[kk] = make_float4(t1[0],t1[1],t1[2],t1[3]);
        }
    }

    float4 O0[8], O1[8];
    #pragma unroll
    for (int kk = 0; kk < 8; ++kk){ O0[kk] = make_float4(0.f,0.f,0.f,0.f); O1[kk] = O0[kk]; }
    float m0 = -1e30f, l0 = 0.f, m1 = -1e30f, l1 = 0.f;

    const size_t kvb = (size_t)blockIdx.y * NN * HID;   // slice-local K/V
    const int jmax_b  = q0b + TQ - 1;                   // loop bound (big tile)
    const int my_jmax = myq0 + TQ - 1;                  // my tile's causal bound

    for (int j0 = 0; j0 <= jmax_b; j0 += TK){
        // ---- stage K,V tile -> fp32 LDS (all 256 threads) ----
        {
            const uint2* ksrc = (const uint2*)(K + kvb + (size_t)j0*HID);
            const uint2* vsrc = (const uint2*)(V + kvb + (size_t)j0*HID);
            #pragma unroll
            for (int it = 0; it < 4; ++it){
                const int f = t + it*256;
                const uint2 u = ksrc[f];
                float4 d;
                d.x = bits2f(u.x<<16); d.y = bits2f(u.x&0xffff0000u);
                d.z = bits2f(u.y<<16); d.w = bits2f(u.y&0xffff0000u);
                kv4[f] = d;
            }
            #pragma unroll
            for (int it = 0; it < 4; ++it){
                const int f = t + it*256;
                const uint2 u = vsrc[f];
                float4 d;
                d.x = bits2f(u.x<<16); d.y = bits2f(u.x&0xffff0000u);
                d.z = bits2f(u.y<<16); d.w = bits2f(u.y&0xffff0000u);
                kv4[1024 + f] = d;
            }
        }
        __syncthreads();

        if (j0 <= my_jmax){              // wave-uniform (tile a waves exit early)
            #pragma unroll
            for (int sub = 0; sub < 4; ++sub){
                const int jb = sub*8;
                float S0[8], S1[8];
                #pragma unroll
                for (int j = 0; j < 8; ++j){
                    const float4* kr = &kv4[(jb+j)*32 + cg];
                    float a0 = 0.f, a1 = 0.f;
                    #pragma unroll
                    for (int kk = 0; kk < 8; ++kk){
                        const float4 kf = kr[kk*4];
                        a0 += q0r[kk].x*kf.x + q0r[kk].y*kf.y + q0r[kk].z*kf.z + q0r[kk].w*kf.w;
                        a1 += q1r[kk].x*kf.x + q1r[kk].y*kf.y + q1r[kk].z*kf.z + q1r[kk].w*kf.w;
                    }
                    a0 += __shfl_xor(a0, 1); a0 += __shfl_xor(a0, 2);
                    a1 += __shfl_xor(a1, 1); a1 += __shfl_xor(a1, 2);
                    const int jj = j0 + jb + j;
                    S0[j] = (jj <= qi0    ) ? a0 : -1e30f;
                    S1[j] = (jj <= qi0 + 1) ? a1 : -1e30f;
                }
                float tm0 = m0, tm1 = m1;
                #pragma unroll
                for (int j = 0; j < 8; ++j){ tm0 = fmaxf(tm0, S0[j]); tm1 = fmaxf(tm1, S1[j]); }
                const float al0 = __expf(m0 - tm0), al1 = __expf(m1 - tm1);
                m0 = tm0; m1 = tm1;
                float ss0 = 0.f, ss1 = 0.f;
                #pragma unroll
                for (int j = 0; j < 8; ++j){
                    S0[j] = __expf(S0[j]-tm0); ss0 += S0[j];
                    S1[j] = __expf(S1[j]-tm1); ss1 += S1[j];
                }
                l0 = l0*al0 + ss0; l1 = l1*al1 + ss1;
                #pragma unroll
                for (int kk = 0; kk < 8; ++kk){
                    O0[kk].x *= al0; O0[kk].y *= al0; O0[kk].z *= al0; O0[kk].w *= al0;
                    O1[kk].x *= al1; O1[kk].y *= al1; O1[kk].z *= al1; O1[kk].w *= al1;
                }
                #pragma unroll
                for (int j = 0; j < 8; ++j){
                    const float p0 = S0[j], p1 = S1[j];
                    const float4* vr = &kv4[1024 + (jb+j)*32 + cg];
                    #pragma unroll
                    for (int kk = 0; kk < 8; ++kk){
                        const float4 vf = vr[kk*4];
                        O0[kk].x += p0*vf.x; O0[kk].y += p0*vf.y; O0[kk].z += p0*vf.z; O0[kk].w += p0*vf.w;
                        O1[kk].x += p1*vf.x; O1[kk].y += p1*vf.y; O1[kk].z += p1*vf.z; O1[kk].w += p1*vf.w;
                    }
                }
            }
        }
        __syncthreads();
    }

    // ---- epilogue: two phases (tile a then tile b), kv reused as cx ----
    #pragma unroll 1
    for (int ph = 0; ph < 2; ++ph){
        const bool mine = (tileA == (ph == 0));
        if (mine){
            const float i0 = 1.f/l0, i1 = 1.f/l1;
            #pragma unroll
            for (int kk = 0; kk < 8; ++kk){
                float4 v0 = O0[kk]; v0.x*=i0; v0.y*=i0; v0.z*=i0; v0.w*=i0;
                float4 v1 = O1[kk]; v1.x*=i1; v1.y*=i1; v1.z*=i1; v1.w*=i1;
                kv4[ tlr0   *32 + kk*4 + cg] = v0;
                kv4[(tlr0+1)*32 + kk*4 + cg] = v1;
            }
        }
        __syncthreads();
        const int q0p  = (ph == 0) ? q0a : q0b;
        const int row  = t >> 2;                 // 0..63
        const int ch0  = (t & 3)*32;
        const int xrow = ph*TQ + row;
        float outv[32];
        #pragma unroll
        for (int k = 0; k < 32; ++k){
            const int ch = ch0 + k;
            float a = t_bo[ch] + skb[ch];
            #pragma unroll
            for (int f = 0; f < FIN; ++f) a += xs[xrow][f]*skw[f*HID + ch];
            outv[k] = a;
        }
        for (int cc = 0; cc < HID; ++cc){
            const int c = (cc + 2*row) & (HID-1);
            const float cxv = kv[row*HID + c];
            #pragma unroll
            for (int k = 0; k < 32; ++k) outv[k] += cxv * t_wo[c*HID + ch0 + k];
        }
        #pragma unroll
        for (int k = 0; k < 32; ++k)
            H1[((size_t)slice*NN + q0p + row)*HID + ch0 + k] = f2b(outv[k]);
        __syncthreads();
    }
}

// ---------------------------------------------------------------------------
// K3: per (b,s): load h1[m] (all 8 m), LN2, node attention (q for m=7 only),
// LN3, MLP -> node feature [128] fp32.
// ---------------------------------------------------------------------------
__global__ void k_mix(const bf16* __restrict__ H1,
                      const float* __restrict__ ln2g, const float* __restrict__ ln2b,
                      const float* __restrict__ s_wq, const float* __restrict__ s_bq,
                      const float* __restrict__ s_wk, const float* __restrict__ s_bk,
                      const float* __restrict__ s_wv, const float* __restrict__ s_bv,
                      const float* __restrict__ s_wo, const float* __restrict__ s_bo,
                      const float* __restrict__ ln3g, const float* __restrict__ ln3b,
                      const float* __restrict__ w1, const float* __restrict__ bm1,
                      const float* __restrict__ w2, const float* __restrict__ bm2,
                      float* __restrict__ Hn)
{
    const int blk = blockIdx.x;          // b*NN + s
    const int b = blk >> 11, s = blk & (NN-1);
    const int h = threadIdx.x;           // 0..127
    __shared__ float h1[TT][HID], z2[TT][HID], k2[TT][HID], v2[TT][HID];
    __shared__ float qv[HID], z3s[HID], hls[2*HID];
    __shared__ float scr[TT];
    __shared__ float rb1[HID], rb2[HID];

    #pragma unroll
    for (int m = 0; m < TT; ++m)
        h1[m][h] = b2f(H1[((size_t)(b*TT + m)*NN + s)*HID + h]);
    __syncthreads();

    const float g2v = ln2g[h], b2v = ln2b[h];
    for (int m = 0; m < TT; ++m){
        const float v = h1[m][h];
        rb1[h] = v; rb2[h] = v*v; __syncthreads();
        for (int st = 64; st > 0; st >>= 1){
            if (h < st){ rb1[h] += rb1[h+st]; rb2[h] += rb2[h+st]; }
            __syncthreads();
        }
        const float mu = rb1[0]*(1.f/HID);
        const float var = rb2[0]*(1.f/HID) - mu*mu;
        const float inv = rsqrtf(var + 1e-5f);
        __syncthreads();
        z2[m][h] = (v - mu)*inv*g2v + b2v;
    }
    __syncthreads();

    {
        float ack[TT], acv[TT];
        const float bkv = s_bk[h], bvv = s_bv[h];
        #pragma unroll
        for (int m = 0; m < TT; ++m){ ack[m] = bkv; acv[m] = bvv; }
        for (int c = 0; c < HID; ++c){
            const float wk = s_wk[c*HID + h];
            const float wv = s_wv[c*HID + h];
            #pragma unroll
            for (int m = 0; m < TT; ++m){ ack[m] += z2[m][c]*wk; acv[m] += z2[m][c]*wv; }
        }
        #pragma unroll
        for (int m = 0; m < TT; ++m){ k2[m][h] = ack[m]; v2[m][h] = acv[m]; }
        float aq = s_bq[h];
        for (int c = 0; c < HID; ++c) aq += z2[TT-1][c]*s_wq[c*HID + h];
        qv[h] = aq;
    }
    __syncthreads();

    if (h < TT){
        float d = 0.f;
        for (int c = 0; c < HID; ++c) d += qv[c]*k2[h][c];
        scr[h] = d * 0.08838834764831845f;
    }
    __syncthreads();
    float mx = -1e30f;
    #pragma unroll
    for (int m = 0; m < TT; ++m) mx = fmaxf(mx, scr[m]);
    float p[TT], se = 0.f;
    #pragma unroll
    for (int m = 0; m < TT; ++m){ p[m] = __expf(scr[m]-mx); se += p[m]; }
    const float isum = 1.f/se;
    float c2 = 0.f;
    #pragma unroll
    for (int m = 0; m < TT; ++m) c2 += p[m]*v2[m][h];
    c2 *= isum;
    __syncthreads();
    qv[h] = c2;
    __syncthreads();

    float o = s_bo[h];
    for (int c = 0; c < HID; ++c) o += qv[c]*s_wo[c*HID + h];
    const float h2 = h1[TT-1][h] + o;

    rb1[h] = h2; rb2[h] = h2*h2; __syncthreads();
    for (int st = 64; st > 0; st >>= 1){
        if (h < st){ rb1[h] += rb1[h+st]; rb2[h] += rb2[h+st]; }
        __syncthreads();
    }
    {
        const float mu = rb1[0]*(1.f/HID);
        const float var = rb2[0]*(1.f/HID) - mu*mu;
        const float inv = rsqrtf(var + 1e-5f);
        __syncthreads();
        z3s[h] = (h2 - mu)*inv*ln3g[h] + ln3b[h];
    }
    __syncthreads();

    float hid0 = bm1[h], hid1 = bm1[h+HID];
    for (int c = 0; c < HID; ++c){
        const float z = z3s[c];
        hid0 += z * w1[c*2*HID + h];
        hid1 += z * w1[c*2*HID + h + HID];
    }
    hls[h] = fmaxf(hid0, 0.f); hls[h+HID] = fmaxf(hid1, 0.f);
    __syncthreads();
    float outv = bm2[h] + h2;
    for (int j = 0; j < 2*HID; ++j) outv += hls[j]*w2[j*HID + h];
    Hn[(size_t)(b*NN + s)*HID + h] = outv;
}

// ---------------------------------------------------------------------------
// GAT
// ---------------------------------------------------------------------------
__device__ __forceinline__ void edge_decode(const int* __restrict__ ei, int e,
                                            int& src, int& dst, bool& dropped)
{
    if (e < NEDGEB){
        const int bb = e >> 15, k = e & (NEDGE-1);
        const int s0 = ei[k], d0 = ei[NEDGE + k];
        src = s0 + bb*NN; dst = d0 + bb*NN;
        dropped = (s0 == d0);     // PyG removes pre-existing self loops
    } else { src = dst = e - NEDGEB; dropped = false; }
}

__global__ void k_gat1_lin(const float* __restrict__ Hn, const float* __restrict__ W,
                           const float* __restrict__ asrc, const float* __restrict__ adst,
                           bf16* __restrict__ hw, float* __restrict__ als, float* __restrict__ ald)
{
    const int nid = blockIdx.x, c = threadIdx.x;   // 128
    __shared__ float hr[HID], r1[HID], r2[HID];
    hr[c] = Hn[(size_t)nid*HID + c];
    __syncthreads();
    float a = 0.f;
    for (int k = 0; k < HID; ++k) a += hr[k]*W[k*HID + c];
    hw[(size_t)nid*HID + c] = f2b(a);
    r1[c] = a*asrc[c]; r2[c] = a*adst[c];
    __syncthreads();
    for (int st = 16; st > 0; st >>= 1){
        if ((c & 31) < st){ r1[c] += r1[c+st]; r2[c] += r2[c+st]; }
        __syncthreads();
    }
    if ((c & 31) == 0){
        als[nid*NHEADS + (c>>5)] = r1[c];
        ald[nid*NHEADS + (c>>5)] = r2[c];
    }
}

__global__ void k_gat_edge1(const int* __restrict__ ei, const float* __restrict__ als,
                            const float* __restrict__ ald, bf16* __restrict__ ex,
                            float* __restrict__ denom)
{
    const int idx = blockIdx.x*blockDim.x + threadIdx.x;
    if (idx >= NETOT*NHEADS) return;
    const int e = idx >> 2, hd = idx & 3;
    int src, dst; bool drop;
    edge_decode(ei, e, src, dst, drop);
    if (drop){ ex[idx] = f2b(0.f); return; }
    float a = als[src*NHEADS + hd] + ald[dst*NHEADS + hd];
    a = a > 0.f ? a : 0.2f*a;
    const bf16 vb = f2b(__expf(a));
    ex[idx] = vb;
    atomicAdd(&denom[dst*NHEADS + hd], b2f(vb));
}

__global__ void k_gat_agg1(const int* __restrict__ ei, const bf16* __restrict__ ex,
                           const float* __restrict__ denom, const bf16* __restrict__ hw,
                           float* __restrict__ agg)
{
    const int t = blockIdx.x*blockDim.x + threadIdx.x;   // NETOT*128
    const int e = t >> 7, c = t & 127;
    if (e >= NETOT) return;
    const float x = b2f(ex[e*NHEADS + (c>>5)]);
    if (x == 0.f) return;
    int src, dst; bool drop;
    edge_decode(ei, e, src, dst, drop);
    const float w = x / denom[dst*NHEADS + (c>>5)];
    atomicAdd(&agg[(size_t)dst*HID + c], w * b2f(hw[(size_t)src*HID + c]));
}

__global__ void k_gat1_fin(const float* __restrict__ agg, const float* __restrict__ bias,
                           bf16* __restrict__ g1)
{
    const int t = blockIdx.x*blockDim.x + threadIdx.x;
    if (t >= NNODE*HID) return;
    const float v = agg[t] + bias[t & 127];
    g1[t] = f2b(v > 0.f ? v : expm1f(v));    // elu
}

__global__ void k_gat2_lin(const bf16* __restrict__ g1, const float* __restrict__ W,
                           const float* __restrict__ asrc, const float* __restrict__ adst,
                           bf16* __restrict__ hw2, float* __restrict__ al2s, float* __restrict__ al2d)
{
    const int nid = blockIdx.x, c = threadIdx.x;    // 64 threads = 1 wave
    __shared__ float hr[HID];
    hr[c] = b2f(g1[(size_t)nid*HID + c]);
    hr[c+64] = b2f(g1[(size_t)nid*HID + c + 64]);
    __syncthreads();
    float a = 0.f;
    for (int k = 0; k < HID; ++k) a += hr[k]*W[k*OUTCH + c];
    hw2[(size_t)nid*OUTCH + c] = f2b(a);
    float s1 = a*asrc[c], s2 = a*adst[c];
    #pragma unroll
    for (int off = 32; off > 0; off >>= 1){
        s1 += __shfl_down(s1, off);
        s2 += __shfl_down(s2, off);
    }
    if (c == 0){ al2s[nid] = s1; al2d[nid] = s2; }
}

__global__ void k_gat_edge2(const int* __restrict__ ei, const float* __restrict__ als,
                            const float* __restrict__ ald, bf16* __restrict__ ex,
                            float* __restrict__ denom)
{
    const int e = blockIdx.x*blockDim.x + threadIdx.x;
    if (e >= NETOT) return;
    int src, dst; bool drop;
    edge_decode(ei, e, src, dst, drop);
    if (drop){ ex[e] = f2b(0.f); return; }
    float a = als[src] + ald[dst];
    a = a > 0.f ? a : 0.2f*a;
    const bf16 vb = f2b(__expf(a));
    ex[e] = vb;
    atomicAdd(&denom[dst], b2f(vb));
}

__global__ void k_gat_agg2(const int* __restrict__ ei, const bf16* __restrict__ ex,
                           const float* __restrict__ denom, const bf16* __restrict__ hw2,
                           float* __restrict__ agg)
{
    const int t = blockIdx.x*blockDim.x + threadIdx.x;   // NETOT*64
    const int e = t >> 6, c = t & 63;
    if (e >= NETOT) return;
    const float x = b2f(ex[e]);
    if (x == 0.f) return;
    int src, dst; bool drop;
    edge_decode(ei, e, src, dst, drop);
    const float w = x / denom[dst];
    atomicAdd(&agg[(size_t)dst*OUTCH + c], w * b2f(hw2[(size_t)src*OUTCH + c]));
}

__global__ void k_final(const float* __restrict__ agg2, const float* __restrict__ g2b,
                        const float* __restrict__ fw, const float* __restrict__ fb,
                        float* __restrict__ out)
{
    const int nid = blockIdx.x, c = threadIdx.x;    // 64
    __shared__ float g[OUTCH];
    g[c] = agg2[(size_t)nid*OUTCH + c] + g2b[c];
    __syncthreads();
    if (c < OUTF){
        float o = fb[c];
        for (int k = 0; k < OUTCH; ++k) o += g[k]*fw[k*OUTF + c];
        const int b = nid >> 11, n = nid & (NN-1);
        out[((size_t)b*OUTF + c)*NN + n] = o;
    }
}

// ---------------------------------------------------------------------------
extern "C" void kernel_launch(void* const* d_in, const int* in_sizes, int n_in,
                              void* d_out, int out_size, void* d_ws, size_t ws_size,
                              hipStream_t stream)
{
    const float* x    = (const float*)d_in[0];
    const int*  ei    = (const int*)d_in[1];
    const float* ln1g = (const float*)d_in[2];  const float* ln1b = (const float*)d_in[3];
    const float* t_wq = (const float*)d_in[4];  const float* t_bq = (const float*)d_in[5];
    const float* t_wk = (const float*)d_in[6];  const float* t_bk = (const float*)d_in[7];
    const float* t_wv = (const float*)d_in[8];  const float* t_bv = (const float*)d_in[9];
    const float* t_wo = (const float*)d_in[10]; const float* t_bo = (const float*)d_in[11];
    const float* skw  = (const float*)d_in[12]; const float* skb  = (const float*)d_in[13];
    const float* ln2g = (const float*)d_in[14]; const float* ln2b = (const float*)d_in[15];
    const float* s_wq = (const float*)d_in[16]; const float* s_bq = (const float*)d_in[17];
    const float* s_wk = (const float*)d_in[18]; const float* s_bk = (const float*)d_in[19];
    const float* s_wv = (const float*)d_in[20]; const float* s_bv = (const float*)d_in[21];
    const float* s_wo = (const float*)d_in[22]; const float* s_bo = (const float*)d_in[23];
    const float* ln3g = (const float*)d_in[24]; const float* ln3b = (const float*)d_in[25];
    const float* w1   = (const float*)d_in[26]; const float* b1   = (const float*)d_in[27];
    const float* w2   = (const float*)d_in[28]; const float* b2   = (const float*)d_in[29];
    const float* g1w  = (const float*)d_in[30];
    const float* g1as = (const float*)d_in[31]; const float* g1ad = (const float*)d_in[32];
    const float* g1b  = (const float*)d_in[33];
    const float* g2w  = (const float*)d_in[34];
    const float* g2as = (const float*)d_in[35]; const float* g2ad = (const float*)d_in[36];
    const float* g2b  = (const float*)d_in[37];
    const float* ffw  = (const float*)d_in[38]; const float* ffb  = (const float*)d_in[39];
    float* out = (float*)d_out;

    const size_t MiB = 1024u*1024u;
    const bool wide = ws_size >= 52*MiB;   // K(16)+V(16)+H1(16)+Hn(4)

    char* base = (char*)d_ws;
    bf16 *Kb, *Vb, *H1;
    float* Hn;
    char* gat_base;
    if (wide){
        Kb = (bf16*)(base + 0*MiB);        // 16 MiB (all 32 slices)
        Vb = (bf16*)(base + 16*MiB);       // 16 MiB
        H1 = (bf16*)(base + 32*MiB);       // 16 MiB
        Hn = (float*)(base + 48*MiB);      // 4 MiB
        gat_base = base;                   // aliases Kb/Vb (dead after attn)
    } else {
        H1 = (bf16*)(base + 0*MiB);        // 16 MiB
        Hn = (float*)(base + 16*MiB);      // 4 MiB
        Kb = (bf16*)(base + 20*MiB);       // 0.5 MiB (one slice)
        Vb = (bf16*)(base + 20*MiB + 512u*1024u);
        gat_base = base;                   // aliases H1 (dead after k_mix)
    }
    // GAT scratch (~12.9 MiB) inside gat_base
    char* w = gat_base;
    auto alloc = [&](size_t bytes){ void* p = (void*)w; w += (bytes + 255) & ~(size_t)255; return p; };
    bf16*  hw1  = (bf16*) alloc((size_t)NNODE*HID*sizeof(bf16));
    float* als1 = (float*)alloc((size_t)NNODE*NHEADS*sizeof(float));
    float* ald1 = (float*)alloc((size_t)NNODE*NHEADS*sizeof(float));
    bf16*  ex1  = (bf16*) alloc((size_t)NETOT*NHEADS*sizeof(bf16));
    float* den1 = (float*)alloc((size_t)NNODE*NHEADS*sizeof(float));
    float* agg1 = (float*)alloc((size_t)NNODE*HID*sizeof(float));
    bf16*  g1o  = (bf16*) alloc((size_t)NNODE*HID*sizeof(bf16));
    bf16*  hw2  = (bf16*) alloc((size_t)NNODE*OUTCH*sizeof(bf16));
    float* als2 = (float*)alloc((size_t)NNODE*sizeof(float));
    float* ald2 = (float*)alloc((size_t)NNODE*sizeof(float));
    bf16*  ex2  = (bf16*) alloc((size_t)NETOT*sizeof(bf16));
    float* den2 = (float*)alloc((size_t)NNODE*sizeof(float));
    float* agg2 = (float*)alloc((size_t)NNODE*OUTCH*sizeof(float));

    // ---- trunk ----
    if (wide){
        k_kv<<<PROWS, HID, 0, stream>>>(x, ln1g, ln1b, t_wk, t_bk, t_wv, t_bv, 0, Kb, Vb);
        k_attn_flash<<<dim3(NPAIR, BM), 256, 0, stream>>>(x, Kb, Vb, ln1g, ln1b, t_wq, t_bq,
                                                          skw, skb, t_wo, t_bo, 0, H1);
    } else {
        for (int s = 0; s < BM; ++s){
            k_kv<<<NN, HID, 0, stream>>>(x, ln1g, ln1b, t_wk, t_bk, t_wv, t_bv, s*NN, Kb, Vb);
            k_attn_flash<<<dim3(NPAIR, 1), 256, 0, stream>>>(x, Kb, Vb, ln1g, ln1b, t_wq, t_bq,
                                                             skw, skb, t_wo, t_bo, s, H1);
        }
    }
    k_mix<<<BB*NN, HID, 0, stream>>>(H1, ln2g, ln2b, s_wq, s_bq, s_wk, s_bk,
                                     s_wv, s_bv, s_wo, s_bo, ln3g, ln3b,
                                     w1, b1, w2, b2, Hn);

    // ---- GAT (accumulators zeroed after k_mix; region was dead/poisoned) ----
    hipMemsetAsync(den1, 0, (size_t)NNODE*NHEADS*sizeof(float), stream);
    hipMemsetAsync(agg1, 0, (size_t)NNODE*HID*sizeof(float), stream);
    hipMemsetAsync(den2, 0, (size_t)NNODE*sizeof(float), stream);
    hipMemsetAsync(agg2, 0, (size_t)NNODE*OUTCH*sizeof(float), stream);

    k_gat1_lin<<<NNODE, HID, 0, stream>>>(Hn, g1w, g1as, g1ad, hw1, als1, ald1);
    k_gat_edge1<<<(NETOT*NHEADS + 255)/256, 256, 0, stream>>>(ei, als1, ald1, ex1, den1);
    k_gat_agg1<<<(NETOT*HID)/256, 256, 0, stream>>>(ei, ex1, den1, hw1, agg1);
    k_gat1_fin<<<(NNODE*HID)/256, 256, 0, stream>>>(agg1, g1b, g1o);
    k_gat2_lin<<<NNODE, OUTCH, 0, stream>>>(g1o, g2w, g2as, g2ad, hw2, als2, ald2);
    k_gat_edge2<<<(NETOT + 255)/256, 256, 0, stream>>>(ei, als2, ald2, ex2, den2);
    k_gat_agg2<<<(NETOT*OUTCH)/256, 256, 0, stream>>>(ei, ex2, den2, hw2, agg2);
    k_final<<<NNODE, OUTCH, 0, stream>>>(agg2, g2b, ffw, ffb, out);
}

// Round 10
// 1578.988 us; speedup vs baseline: 2.3369x; 2.3369x over previous
//
#include <hip/hip_runtime.h>
#include <hip/hip_bf16.h>
#include <stdint.h>

// ---------------------------------------------------------------------------
// PFGAT: [B,T,N,F]=[4,8,2048,16] transformer (causal attn over N per (b,t),
// node attn over T-slots, MLP at last slot) -> 2x GATConv -> FFN -> [B,14,N].
// fp32 I/O, fp32 compute, bf16 intermediate storage.
// R10: MFMA flash attention (16x16x32 bf16): Q A-frags in regs, K B-frags
// direct from global, V pre-transposed (Vt[ch][key]) for contiguous B-frags,
// P C->A layout via per-wave LDS roundtrip, barrier-free K-loop, biggest-
// tile-first dispatch for causal balance.
// ---------------------------------------------------------------------------

#define BB     4
#define TT     8
#define NN     2048
#define FIN    16
#define HID    128
#define BM     (BB*TT)            // 32 attention slices
#define PROWS  (BM*NN)            // 65536 rows
#define NHEADS 4
#define OUTCH  64
#define OUTF   14
#define NEDGE  32768
#define NEDGEB (NEDGE*BB)         // 131072
#define NNODE  (BB*NN)            // 8192
#define NETOT  (NEDGEB + NNODE)   // 139264 (edges + self loops)

#define TQ     64                 // query tile (rows per block)
#define NTILE  (NN/TQ)            // 32 query tiles per slice

typedef __hip_bfloat16 bf16;
typedef __attribute__((ext_vector_type(8))) short bf16x8;   // MFMA A/B frag
typedef __attribute__((ext_vector_type(4))) float f32x4;    // MFMA C/D frag

__device__ __forceinline__ float b2f(bf16 v){ return __bfloat162float(v); }
__device__ __forceinline__ bf16  f2b(float f){ return __float2bfloat16(f); }

// ---------------------------------------------------------------------------
// K1: per row: LN1 over F=16 -> k,v projections; K row-major, V transposed
// (Vt[slice][ch][key]) for MFMA B-fragment contiguity.
// ---------------------------------------------------------------------------
__global__ void k_kv(const float* __restrict__ x,
                     const float* __restrict__ g1, const float* __restrict__ bb1,
                     const float* __restrict__ wk, const float* __restrict__ bk,
                     const float* __restrict__ wv, const float* __restrict__ bv,
                     int in_off, bf16* __restrict__ K, bf16* __restrict__ Vt)
{
    const int rloc = blockIdx.x;
    const int rin  = rloc + in_off;
    const int h = threadIdx.x;       // 0..127
    __shared__ float xr[FIN], lnv[FIN];
    if (h < FIN) xr[h] = x[(size_t)rin*FIN + h];
    __syncthreads();
    float mu = 0.f;
    #pragma unroll
    for (int f = 0; f < FIN; ++f) mu += xr[f];
    mu *= (1.f/FIN);
    float var = 0.f;
    #pragma unroll
    for (int f = 0; f < FIN; ++f){ float d = xr[f]-mu; var += d*d; }
    var *= (1.f/FIN);
    const float inv = rsqrtf(var + 1e-5f);
    if (h < FIN) lnv[h] = (xr[h]-mu)*inv*g1[h] + bb1[h];
    __syncthreads();
    float ak = bk[h], av = bv[h];
    #pragma unroll
    for (int f = 0; f < FIN; ++f){
        const float l = lnv[f];
        ak += l * wk[f*HID + h];
        av += l * wv[f*HID + h];
    }
    K[(size_t)rloc*HID + h] = f2b(ak);
    const int slice = rloc >> 11;            // 0 in narrow mode
    const int key   = rloc & (NN-1);
    Vt[((size_t)slice*HID + h)*NN + key] = f2b(av);
}

// ---------------------------------------------------------------------------
// K2 (MFMA flash): block = one 64-row Q tile; 4 waves, wave w owns rows
// 16w..16w+15. Q A-frags (4x bf16x8) in registers; per 32-key step:
// S = Q.K^T via 8 MFMAs (K B-frags 16B global loads), mask+online softmax
// (16-lane shfl_xor reduces), P -> LDS (C-layout write, A-layout b128 read),
// PV via 8 MFMAs (Vt B-frags 16B global loads) into 8 C-frags.
// No barriers in the K-loop. Fused epilogue H1 = skip + ctx@t_wo + t_bo.
// Dispatch biggest tile first (blockIdx.x=0 -> tile 31) for causal balance.
// ---------------------------------------------------------------------------
__global__ __launch_bounds__(256)
void k_attn_mfma(const float* __restrict__ x,
                 const bf16* __restrict__ K, const bf16* __restrict__ Vt,
                 const float* __restrict__ g1, const float* __restrict__ bb1,
                 const float* __restrict__ wq, const float* __restrict__ bq,
                 const float* __restrict__ skw, const float* __restrict__ skb,
                 const float* __restrict__ t_wo, const float* __restrict__ t_bo,
                 int slice_off, bf16* __restrict__ H1)
{
    const int tile  = (NTILE-1) - (int)blockIdx.x;   // big tiles first
    const int q0    = tile*TQ;
    const int slice = blockIdx.y + slice_off;
    const int t     = threadIdx.x;
    const int w     = t >> 6;            // wave 0..3
    const int lane  = t & 63;
    const int quad  = lane >> 4;
    const int l16   = lane & 15;
    const int wr0   = w*16;              // wave's first local row

    __shared__ float xs [TQ][FIN];                 // raw x rows (skip)
    __shared__ float lns[TQ][FIN];                 // LN1(x) rows
    __shared__ bf16  Qs [TQ][136];                 // Q (scaled) bf16; cx later
    __shared__ bf16  Ps [4][16][40];               // per-wave P roundtrip

    // ---- stage x rows ----
    for (int u = t; u < TQ*FIN; u += 256)
        ((float*)xs)[u] = x[((size_t)slice*NN + q0)*FIN + u];
    __syncthreads();
    // ---- LN1 per row ----
    if (t < TQ){
        float mu = 0.f;
        #pragma unroll
        for (int f = 0; f < FIN; ++f) mu += xs[t][f];
        mu *= (1.f/FIN);
        float var = 0.f;
        #pragma unroll
        for (int f = 0; f < FIN; ++f){ float d = xs[t][f]-mu; var += d*d; }
        var *= (1.f/FIN);
        const float inv = rsqrtf(var + 1e-5f);
        #pragma unroll
        for (int f = 0; f < FIN; ++f)
            lns[t][f] = (xs[t][f]-mu)*inv*g1[f] + bb1[f];
    }
    __syncthreads();
    // ---- Q (scale folded) -> Qs bf16 ----
    {
        const int r = t >> 2, c0 = (t & 3)*32;
        const float scale = 0.08838834764831845f;   // 1/sqrt(128)
        #pragma unroll
        for (int k = 0; k < 32; ++k){
            const int ch = c0 + k;
            float a = bq[ch];
            #pragma unroll
            for (int f = 0; f < FIN; ++f) a += lns[r][f]*wq[f*HID + ch];
            Qs[r][ch] = f2b(a*scale);
        }
    }
    __syncthreads();

    // ---- Q A-frags: A[m=l16][k=quad*8+j], k-step ks*32 ----
    bf16x8 qf[4];
    #pragma unroll
    for (int ks = 0; ks < 4; ++ks)
        qf[ks] = *(const bf16x8*)(const void*)&Qs[wr0 + l16][ks*32 + quad*8];

    f32x4 O[8];
    #pragma unroll
    for (int ct = 0; ct < 8; ++ct) O[ct] = (f32x4){0.f,0.f,0.f,0.f};
    float m_[4] = {-1e30f,-1e30f,-1e30f,-1e30f};
    float l_[4] = {0.f,0.f,0.f,0.f};

    const size_t kb = (size_t)blockIdx.y * NN * HID;            // K slice base
    const size_t vb = (size_t)blockIdx.y * (size_t)HID * NN;    // Vt slice base
    const int jend = q0 + wr0 + 15;         // wave-uniform causal bound
    const int brow = q0 + wr0 + quad*4;     // +reg = my global q-row

    for (int j0 = 0; j0 <= jend; j0 += 32){
        // ---- S tiles: cols j0..j0+15 (S0) and j0+16..j0+31 (S1) ----
        f32x4 S0 = (f32x4){0.f,0.f,0.f,0.f}, S1 = S0;
        #pragma unroll
        for (int ks = 0; ks < 4; ++ks){
            const bf16x8 kf0 = *(const bf16x8*)(const void*)
                (K + kb + (size_t)(j0      + l16)*HID + ks*32 + quad*8);
            const bf16x8 kf1 = *(const bf16x8*)(const void*)
                (K + kb + (size_t)(j0 + 16 + l16)*HID + ks*32 + quad*8);
            S0 = __builtin_amdgcn_mfma_f32_16x16x32_bf16(qf[ks], kf0, S0, 0, 0, 0);
            S1 = __builtin_amdgcn_mfma_f32_16x16x32_bf16(qf[ks], kf1, S1, 0, 0, 0);
        }
        // ---- mask + online softmax (per reg = row brow+r) ----
        const int c0j = j0 + l16, c1j = c0j + 16;
        float alpha[4];
        #pragma unroll
        for (int r = 0; r < 4; ++r){
            float s0 = (c0j <= brow + r) ? S0[r] : -1e30f;
            float s1 = (c1j <= brow + r) ? S1[r] : -1e30f;
            float tmx = fmaxf(s0, s1);
            tmx = fmaxf(tmx, __shfl_xor(tmx, 1));
            tmx = fmaxf(tmx, __shfl_xor(tmx, 2));
            tmx = fmaxf(tmx, __shfl_xor(tmx, 4));
            tmx = fmaxf(tmx, __shfl_xor(tmx, 8));
            const float mn = fmaxf(m_[r], tmx);
            alpha[r] = __expf(m_[r] - mn);
            m_[r] = mn;
            const bf16 hb0 = f2b(__expf(s0 - mn));
            const bf16 hb1 = f2b(__expf(s1 - mn));
            Ps[w][quad*4 + r][l16]      = hb0;
            Ps[w][quad*4 + r][l16 + 16] = hb1;
            float rs = b2f(hb0) + b2f(hb1);     // sum the rounded P
            rs += __shfl_xor(rs, 1);
            rs += __shfl_xor(rs, 2);
            rs += __shfl_xor(rs, 4);
            rs += __shfl_xor(rs, 8);
            l_[r] = l_[r]*alpha[r] + rs;
        }
        #pragma unroll
        for (int ct = 0; ct < 8; ++ct){
            O[ct][0] *= alpha[0]; O[ct][1] *= alpha[1];
            O[ct][2] *= alpha[2]; O[ct][3] *= alpha[3];
        }
        // ---- PV: A = P (A-layout via LDS), B = Vt frags ----
        const bf16x8 pf = *(const bf16x8*)(const void*)&Ps[w][l16][quad*8];
        #pragma unroll
        for (int ct = 0; ct < 8; ++ct){
            const bf16x8 vf = *(const bf16x8*)(const void*)
                (Vt + vb + (size_t)(ct*16 + l16)*NN + j0 + quad*8);
            O[ct] = __builtin_amdgcn_mfma_f32_16x16x32_bf16(pf, vf, O[ct], 0, 0, 0);
        }
    }

    // ---- normalize -> cx (bf16) into Qs (Q-frags already in regs) ----
    {
        float inv[4];
        #pragma unroll
        for (int r = 0; r < 4; ++r) inv[r] = 1.f/l_[r];
        #pragma unroll
        for (int ct = 0; ct < 8; ++ct)
        #pragma unroll
        for (int r = 0; r < 4; ++r)
            Qs[wr0 + quad*4 + r][ct*16 + l16] = f2b(O[ct][r]*inv[r]);
    }
    // ---- epilogue: rows t>>2 belong to this thread's wave -> no barrier ----
    {
        const int row = t >> 2, ch0 = (t & 3)*32;
        float outv[32];
        #pragma unroll
        for (int k = 0; k < 32; ++k){
            const int ch = ch0 + k;
            float a = t_bo[ch] + skb[ch];
            #pragma unroll
            for (int f = 0; f < FIN; ++f) a += xs[row][f]*skw[f*HID + ch];
            outv[k] = a;
        }
        for (int cc = 0; cc < HID; ++cc){
            const int c = (cc + 2*row) & (HID-1);
            const float cxv = b2f(Qs[row][c]);
            #pragma unroll
            for (int k = 0; k < 32; ++k) outv[k] += cxv * t_wo[c*HID + ch0 + k];
        }
        #pragma unroll
        for (int k = 0; k < 32; ++k)
            H1[((size_t)slice*NN + q0 + row)*HID + ch0 + k] = f2b(outv[k]);
    }
}

// ---------------------------------------------------------------------------
// K3: per (b,s): load h1[m] (all 8 m), LN2, node attention (q for m=7 only),
// LN3, MLP -> node feature [128] fp32.
// ---------------------------------------------------------------------------
__global__ void k_mix(const bf16* __restrict__ H1,
                      const float* __restrict__ ln2g, const float* __restrict__ ln2b,
                      const float* __restrict__ s_wq, const float* __restrict__ s_bq,
                      const float* __restrict__ s_wk, const float* __restrict__ s_bk,
                      const float* __restrict__ s_wv, const float* __restrict__ s_bv,
                      const float* __restrict__ s_wo, const float* __restrict__ s_bo,
                      const float* __restrict__ ln3g, const float* __restrict__ ln3b,
                      const float* __restrict__ w1, const float* __restrict__ bm1,
                      const float* __restrict__ w2, const float* __restrict__ bm2,
                      float* __restrict__ Hn)
{
    const int blk = blockIdx.x;          // b*NN + s
    const int b = blk >> 11, s = blk & (NN-1);
    const int h = threadIdx.x;           // 0..127
    __shared__ float h1[TT][HID], z2[TT][HID], k2[TT][HID], v2[TT][HID];
    __shared__ float qv[HID], z3s[HID], hls[2*HID];
    __shared__ float scr[TT];
    __shared__ float rb1[HID], rb2[HID];

    #pragma unroll
    for (int m = 0; m < TT; ++m)
        h1[m][h] = b2f(H1[((size_t)(b*TT + m)*NN + s)*HID + h]);
    __syncthreads();

    const float g2v = ln2g[h], b2v = ln2b[h];
    for (int m = 0; m < TT; ++m){
        const float v = h1[m][h];
        rb1[h] = v; rb2[h] = v*v; __syncthreads();
        for (int st = 64; st > 0; st >>= 1){
            if (h < st){ rb1[h] += rb1[h+st]; rb2[h] += rb2[h+st]; }
            __syncthreads();
        }
        const float mu = rb1[0]*(1.f/HID);
        const float var = rb2[0]*(1.f/HID) - mu*mu;
        const float inv = rsqrtf(var + 1e-5f);
        __syncthreads();
        z2[m][h] = (v - mu)*inv*g2v + b2v;
    }
    __syncthreads();

    {
        float ack[TT], acv[TT];
        const float bkv = s_bk[h], bvv = s_bv[h];
        #pragma unroll
        for (int m = 0; m < TT; ++m){ ack[m] = bkv; acv[m] = bvv; }
        for (int c = 0; c < HID; ++c){
            const float wk = s_wk[c*HID + h];
            const float wv = s_wv[c*HID + h];
            #pragma unroll
            for (int m = 0; m < TT; ++m){ ack[m] += z2[m][c]*wk; acv[m] += z2[m][c]*wv; }
        }
        #pragma unroll
        for (int m = 0; m < TT; ++m){ k2[m][h] = ack[m]; v2[m][h] = acv[m]; }
        float aq = s_bq[h];
        for (int c = 0; c < HID; ++c) aq += z2[TT-1][c]*s_wq[c*HID + h];
        qv[h] = aq;
    }
    __syncthreads();

    if (h < TT){
        float d = 0.f;
        for (int c = 0; c < HID; ++c) d += qv[c]*k2[h][c];
        scr[h] = d * 0.08838834764831845f;
    }
    __syncthreads();
    float mx = -1e30f;
    #pragma unroll
    for (int m = 0; m < TT; ++m) mx = fmaxf(mx, scr[m]);
    float p[TT], se = 0.f;
    #pragma unroll
    for (int m = 0; m < TT; ++m){ p[m] = __expf(scr[m]-mx); se += p[m]; }
    const float isum = 1.f/se;
    float c2 = 0.f;
    #pragma unroll
    for (int m = 0; m < TT; ++m) c2 += p[m]*v2[m][h];
    c2 *= isum;
    __syncthreads();
    qv[h] = c2;
    __syncthreads();

    float o = s_bo[h];
    for (int c = 0; c < HID; ++c) o += qv[c]*s_wo[c*HID + h];
    const float h2 = h1[TT-1][h] + o;

    rb1[h] = h2; rb2[h] = h2*h2; __syncthreads();
    for (int st = 64; st > 0; st >>= 1){
        if (h < st){ rb1[h] += rb1[h+st]; rb2[h] += rb2[h+st]; }
        __syncthreads();
    }
    {
        const float mu = rb1[0]*(1.f/HID);
        const float var = rb2[0]*(1.f/HID) - mu*mu;
        const float inv = rsqrtf(var + 1e-5f);
        __syncthreads();
        z3s[h] = (h2 - mu)*inv*ln3g[h] + ln3b[h];
    }
    __syncthreads();

    float hid0 = bm1[h], hid1 = bm1[h+HID];
    for (int c = 0; c < HID; ++c){
        const float z = z3s[c];
        hid0 += z * w1[c*2*HID + h];
        hid1 += z * w1[c*2*HID + h + HID];
    }
    hls[h] = fmaxf(hid0, 0.f); hls[h+HID] = fmaxf(hid1, 0.f);
    __syncthreads();
    float outv = bm2[h] + h2;
    for (int j = 0; j < 2*HID; ++j) outv += hls[j]*w2[j*HID + h];
    Hn[(size_t)(b*NN + s)*HID + h] = outv;
}

// ---------------------------------------------------------------------------
// GAT
// ---------------------------------------------------------------------------
__device__ __forceinline__ void edge_decode(const int* __restrict__ ei, int e,
                                            int& src, int& dst, bool& dropped)
{
    if (e < NEDGEB){
        const int bb = e >> 15, k = e & (NEDGE-1);
        const int s0 = ei[k], d0 = ei[NEDGE + k];
        src = s0 + bb*NN; dst = d0 + bb*NN;
        dropped = (s0 == d0);     // PyG removes pre-existing self loops
    } else { src = dst = e - NEDGEB; dropped = false; }
}

__global__ void k_gat1_lin(const float* __restrict__ Hn, const float* __restrict__ W,
                           const float* __restrict__ asrc, const float* __restrict__ adst,
                           bf16* __restrict__ hw, float* __restrict__ als, float* __restrict__ ald)
{
    const int nid = blockIdx.x, c = threadIdx.x;   // 128
    __shared__ float hr[HID], r1[HID], r2[HID];
    hr[c] = Hn[(size_t)nid*HID + c];
    __syncthreads();
    float a = 0.f;
    for (int k = 0; k < HID; ++k) a += hr[k]*W[k*HID + c];
    hw[(size_t)nid*HID + c] = f2b(a);
    r1[c] = a*asrc[c]; r2[c] = a*adst[c];
    __syncthreads();
    for (int st = 16; st > 0; st >>= 1){
        if ((c & 31) < st){ r1[c] += r1[c+st]; r2[c] += r2[c+st]; }
        __syncthreads();
    }
    if ((c & 31) == 0){
        als[nid*NHEADS + (c>>5)] = r1[c];
        ald[nid*NHEADS + (c>>5)] = r2[c];
    }
}

__global__ void k_gat_edge1(const int* __restrict__ ei, const float* __restrict__ als,
                            const float* __restrict__ ald, bf16* __restrict__ ex,
                            float* __restrict__ denom)
{
    const int idx = blockIdx.x*blockDim.x + threadIdx.x;
    if (idx >= NETOT*NHEADS) return;
    const int e = idx >> 2, hd = idx & 3;
    int src, dst; bool drop;
    edge_decode(ei, e, src, dst, drop);
    if (drop){ ex[idx] = f2b(0.f); return; }
    float a = als[src*NHEADS + hd] + ald[dst*NHEADS + hd];
    a = a > 0.f ? a : 0.2f*a;
    const bf16 vb = f2b(__expf(a));
    ex[idx] = vb;
    atomicAdd(&denom[dst*NHEADS + hd], b2f(vb));
}

__global__ void k_gat_agg1(const int* __restrict__ ei, const bf16* __restrict__ ex,
                           const float* __restrict__ denom, const bf16* __restrict__ hw,
                           float* __restrict__ agg)
{
    const int t = blockIdx.x*blockDim.x + threadIdx.x;   // NETOT*128
    const int e = t >> 7, c = t & 127;
    if (e >= NETOT) return;
    const float x = b2f(ex[e*NHEADS + (c>>5)]);
    if (x == 0.f) return;
    int src, dst; bool drop;
    edge_decode(ei, e, src, dst, drop);
    const float w = x / denom[dst*NHEADS + (c>>5)];
    atomicAdd(&agg[(size_t)dst*HID + c], w * b2f(hw[(size_t)src*HID + c]));
}

__global__ void k_gat1_fin(const float* __restrict__ agg, const float* __restrict__ bias,
                           bf16* __restrict__ g1)
{
    const int t = blockIdx.x*blockDim.x + threadIdx.x;
    if (t >= NNODE*HID) return;
    const float v = agg[t] + bias[t & 127];
    g1[t] = f2b(v > 0.f ? v : expm1f(v));    // elu
}

__global__ void k_gat2_lin(const bf16* __restrict__ g1, const float* __restrict__ W,
                           const float* __restrict__ asrc, const float* __restrict__ adst,
                           bf16* __restrict__ hw2, float* __restrict__ al2s, float* __restrict__ al2d)
{
    const int nid = blockIdx.x, c = threadIdx.x;    // 64 threads = 1 wave
    __shared__ float hr[HID];
    hr[c] = b2f(g1[(size_t)nid*HID + c]);
    hr[c+64] = b2f(g1[(size_t)nid*HID + c + 64]);
    __syncthreads();
    float a = 0.f;
    for (int k = 0; k < HID; ++k) a += hr[k]*W[k*OUTCH + c];
    hw2[(size_t)nid*OUTCH + c] = f2b(a);
    float s1 = a*asrc[c], s2 = a*adst[c];
    #pragma unroll
    for (int off = 32; off > 0; off >>= 1){
        s1 += __shfl_down(s1, off);
        s2 += __shfl_down(s2, off);
    }
    if (c == 0){ al2s[nid] = s1; al2d[nid] = s2; }
}

__global__ void k_gat_edge2(const int* __restrict__ ei, const float* __restrict__ als,
                            const float* __restrict__ ald, bf16* __restrict__ ex,
                            float* __restrict__ denom)
{
    const int e = blockIdx.x*blockDim.x + threadIdx.x;
    if (e >= NETOT) return;
    int src, dst; bool drop;
    edge_decode(ei, e, src, dst, drop);
    if (drop){ ex[e] = f2b(0.f); return; }
    float a = als[src] + ald[dst];
    a = a > 0.f ? a : 0.2f*a;
    const bf16 vb = f2b(__expf(a));
    ex[e] = vb;
    atomicAdd(&denom[dst], b2f(vb));
}

__global__ void k_gat_agg2(const int* __restrict__ ei, const bf16* __restrict__ ex,
                           const float* __restrict__ denom, const bf16* __restrict__ hw2,
                           float* __restrict__ agg)
{
    const int t = blockIdx.x*blockDim.x + threadIdx.x;   // NETOT*64
    const int e = t >> 6, c = t & 63;
    if (e >= NETOT) return;
    const float x = b2f(ex[e]);
    if (x == 0.f) return;
    int src, dst; bool drop;
    edge_decode(ei, e, src, dst, drop);
    const float w = x / denom[dst];
    atomicAdd(&agg[(size_t)dst*OUTCH + c], w * b2f(hw2[(size_t)src*OUTCH + c]));
}

__global__ void k_final(const float* __restrict__ agg2, const float* __restrict__ g2b,
                        const float* __restrict__ fw, const float* __restrict__ fb,
                        float* __restrict__ out)
{
    const int nid = blockIdx.x, c = threadIdx.x;    // 64
    __shared__ float g[OUTCH];
    g[c] = agg2[(size_t)nid*OUTCH + c] + g2b[c];
    __syncthreads();
    if (c < OUTF){
        float o = fb[c];
        for (int k = 0; k < OUTCH; ++k) o += g[k]*fw[k*OUTF + c];
        const int b = nid >> 11, n = nid & (NN-1);
        out[((size_t)b*OUTF + c)*NN + n] = o;
    }
}

// ---------------------------------------------------------------------------
extern "C" void kernel_launch(void* const* d_in, const int* in_sizes, int n_in,
                              void* d_out, int out_size, void* d_ws, size_t ws_size,
                              hipStream_t stream)
{
    const float* x    = (const float*)d_in[0];
    const int*  ei    = (const int*)d_in[1];
    const float* ln1g = (const float*)d_in[2];  const float* ln1b = (const float*)d_in[3];
    const float* t_wq = (const float*)d_in[4];  const float* t_bq = (const float*)d_in[5];
    const float* t_wk = (const float*)d_in[6];  const float* t_bk = (const float*)d_in[7];
    const float* t_wv = (const float*)d_in[8];  const float* t_bv = (const float*)d_in[9];
    const float* t_wo = (const float*)d_in[10]; const float* t_bo = (const float*)d_in[11];
    const float* skw  = (const float*)d_in[12]; const float* skb  = (const float*)d_in[13];
    const float* ln2g = (const float*)d_in[14]; const float* ln2b = (const float*)d_in[15];
    const float* s_wq = (const float*)d_in[16]; const float* s_bq = (const float*)d_in[17];
    const float* s_wk = (const float*)d_in[18]; const float* s_bk = (const float*)d_in[19];
    const float* s_wv = (const float*)d_in[20]; const float* s_bv = (const float*)d_in[21];
    const float* s_wo = (const float*)d_in[22]; const float* s_bo = (const float*)d_in[23];
    const float* ln3g = (const float*)d_in[24]; const float* ln3b = (const float*)d_in[25];
    const float* w1   = (const float*)d_in[26]; const float* b1   = (const float*)d_in[27];
    const float* w2   = (const float*)d_in[28]; const float* b2   = (const float*)d_in[29];
    const float* g1w  = (const float*)d_in[30];
    const float* g1as = (const float*)d_in[31]; const float* g1ad = (const float*)d_in[32];
    const float* g1b  = (const float*)d_in[33];
    const float* g2w  = (const float*)d_in[34];
    const float* g2as = (const float*)d_in[35]; const float* g2ad = (const float*)d_in[36];
    const float* g2b  = (const float*)d_in[37];
    const float* ffw  = (const float*)d_in[38]; const float* ffb  = (const float*)d_in[39];
    float* out = (float*)d_out;

    const size_t MiB = 1024u*1024u;
    const bool wide = ws_size >= 52*MiB;   // K(16)+Vt(16)+H1(16)+Hn(4)

    char* base = (char*)d_ws;
    bf16 *Kb, *Vtb, *H1;
    float* Hn;
    char* gat_base;
    if (wide){
        Kb  = (bf16*)(base + 0*MiB);       // 16 MiB (all 32 slices, row-major)
        Vtb = (bf16*)(base + 16*MiB);      // 16 MiB ([slice][ch][key])
        H1  = (bf16*)(base + 32*MiB);      // 16 MiB
        Hn  = (float*)(base + 48*MiB);     // 4 MiB
        gat_base = base;                   // aliases Kb/Vtb (dead after attn)
    } else {
        H1  = (bf16*)(base + 0*MiB);       // 16 MiB
        Hn  = (float*)(base + 16*MiB);     // 4 MiB
        Kb  = (bf16*)(base + 20*MiB);      // 0.5 MiB (one slice)
        Vtb = (bf16*)(base + 20*MiB + 512u*1024u);
        gat_base = base;                   // aliases H1 (dead after k_mix)
    }
    // GAT scratch (~12.9 MiB) inside gat_base
    char* w = gat_base;
    auto alloc = [&](size_t bytes){ void* p = (void*)w; w += (bytes + 255) & ~(size_t)255; return p; };
    bf16*  hw1  = (bf16*) alloc((size_t)NNODE*HID*sizeof(bf16));
    float* als1 = (float*)alloc((size_t)NNODE*NHEADS*sizeof(float));
    float* ald1 = (float*)alloc((size_t)NNODE*NHEADS*sizeof(float));
    bf16*  ex1  = (bf16*) alloc((size_t)NETOT*NHEADS*sizeof(bf16));
    float* den1 = (float*)alloc((size_t)NNODE*NHEADS*sizeof(float));
    float* agg1 = (float*)alloc((size_t)NNODE*HID*sizeof(float));
    bf16*  g1o  = (bf16*) alloc((size_t)NNODE*HID*sizeof(bf16));
    bf16*  hw2  = (bf16*) alloc((size_t)NNODE*OUTCH*sizeof(bf16));
    float* als2 = (float*)alloc((size_t)NNODE*sizeof(float));
    float* ald2 = (float*)alloc((size_t)NNODE*sizeof(float));
    bf16*  ex2  = (bf16*) alloc((size_t)NETOT*sizeof(bf16));
    float* den2 = (float*)alloc((size_t)NNODE*sizeof(float));
    float* agg2 = (float*)alloc((size_t)NNODE*OUTCH*sizeof(float));

    // ---- trunk ----
    if (wide){
        k_kv<<<PROWS, HID, 0, stream>>>(x, ln1g, ln1b, t_wk, t_bk, t_wv, t_bv, 0, Kb, Vtb);
        k_attn_mfma<<<dim3(NTILE, BM), 256, 0, stream>>>(x, Kb, Vtb, ln1g, ln1b, t_wq, t_bq,
                                                         skw, skb, t_wo, t_bo, 0, H1);
    } else {
        for (int s = 0; s < BM; ++s){
            k_kv<<<NN, HID, 0, stream>>>(x, ln1g, ln1b, t_wk, t_bk, t_wv, t_bv, s*NN, Kb, Vtb);
            k_attn_mfma<<<dim3(NTILE, 1), 256, 0, stream>>>(x, Kb, Vtb, ln1g, ln1b, t_wq, t_bq,
                                                            skw, skb, t_wo, t_bo, s, H1);
        }
    }
    k_mix<<<BB*NN, HID, 0, stream>>>(H1, ln2g, ln2b, s_wq, s_bq, s_wk, s_bk,
                                     s_wv, s_bv, s_wo, s_bo, ln3g, ln3b,
                                     w1, b1, w2, b2, Hn);

    // ---- GAT (accumulators zeroed after k_mix; region was dead/poisoned) ----
    hipMemsetAsync(den1, 0, (size_t)NNODE*NHEADS*sizeof(float), stream);
    hipMemsetAsync(agg1, 0, (size_t)NNODE*HID*sizeof(float), stream);
    hipMemsetAsync(den2, 0, (size_t)NNODE*sizeof(float), stream);
    hipMemsetAsync(agg2, 0, (size_t)NNODE*OUTCH*sizeof(float), stream);

    k_gat1_lin<<<NNODE, HID, 0, stream>>>(Hn, g1w, g1as, g1ad, hw1, als1, ald1);
    k_gat_edge1<<<(NETOT*NHEADS + 255)/256, 256, 0, stream>>>(ei, als1, ald1, ex1, den1);
    k_gat_agg1<<<(NETOT*HID)/256, 256, 0, stream>>>(ei, ex1, den1, hw1, agg1);
    k_gat1_fin<<<(NNODE*HID)/256, 256, 0, stream>>>(agg1, g1b, g1o);
    k_gat2_lin<<<NNODE, OUTCH, 0, stream>>>(g1o, g2w, g2as, g2ad, hw2, als2, ald2);
    k_gat_edge2<<<(NETOT + 255)/256, 256, 0, stream>>>(ei, als2, ald2, ex2, den2);
    k_gat_agg2<<<(NETOT*OUTCH)/256, 256, 0, stream>>>(ei, ex2, den2, hw2, agg2);
    k_final<<<NNODE, OUTCH, 0, stream>>>(agg2, g2b, ffw, ffb, out);
}